// Round 1
// baseline (10295.629 us; speedup 1.0000x reference)
//
#include <hip/hip_runtime.h>

// LSTM: B=64, S=512, I=H=O=1024.
// Strategy: bf16 MFMA everywhere (threshold is 2% of |ref|max).
//  - pack_weights: 9x [1024][1024] fp32 -> bf16 transposed/packed panels
//  - convert_x: x [B][S][I] fp32 -> xT [S][B][I] bf16
//  - 512x lstm_step: per block 16 hidden units; fused K=2048 ([h | x_t] @ [W_h; W_i]),
//    wave-split-K, LDS reduce, fused gate epilogue. h double-buffered.
//  - final_gemm: out = h_T @ W_y (fp32 out)

typedef __bf16 bfv8 __attribute__((ext_vector_type(8)));
typedef float f32x4 __attribute__((ext_vector_type(4)));

__device__ __forceinline__ unsigned short f2bf(float x) {
    union { float f; unsigned int u; } v; v.f = x;
    unsigned int r = (v.u + 0x7FFFu + ((v.u >> 16) & 1u)) >> 16;
    return (unsigned short)r;
}

struct SrcPtrs { const float* p[9]; };

// ---------------------------------------------------------------------------
// Weight pack: tiled transpose fp32 [1024][1024] -> bf16 [col-panel][k]
// z 0..3: W_h{i,f,o,g} -> Whp[(n/16)*64 + g*16 + n%16][k]
// z 4..7: W_i{i,f,o,g} -> Wip[same][k]
// z 8   : W_y          -> Wy [n][k]
// ---------------------------------------------------------------------------
__global__ __launch_bounds__(256) void pack_weights(SrcPtrs sp,
                                                    unsigned short* __restrict__ Whp,
                                                    unsigned short* __restrict__ Wip,
                                                    unsigned short* __restrict__ Wy) {
    __shared__ float tile[64][65];
    const int z = blockIdx.z;
    const float* __restrict__ src = sp.p[z];
    const int n0 = blockIdx.x * 64, k0 = blockIdx.y * 64;
    const int tc = threadIdx.x & 63, tq = threadIdx.x >> 6;

    #pragma unroll
    for (int r = 0; r < 16; ++r) {
        const int kk = tq * 16 + r;
        tile[kk][tc] = src[(size_t)(k0 + kk) * 1024 + n0 + tc];
    }
    __syncthreads();
    #pragma unroll
    for (int r = 0; r < 16; ++r) {
        const int nl = tq * 16 + r;
        const int n = n0 + nl;
        const int k = k0 + tc;
        const unsigned short v = f2bf(tile[tc][nl]);
        if (z < 4) {
            Whp[(size_t)(((n >> 4) << 6) + (z << 4) + (n & 15)) * 1024 + k] = v;
        } else if (z < 8) {
            Wip[(size_t)(((n >> 4) << 6) + ((z - 4) << 4) + (n & 15)) * 1024 + k] = v;
        } else {
            Wy[(size_t)n * 1024 + k] = v;
        }
    }
}

// ---------------------------------------------------------------------------
// x [64][512][1024] fp32 -> xT [512][64][1024] bf16 (row permute + convert)
// ---------------------------------------------------------------------------
__global__ __launch_bounds__(256) void convert_x(const float* __restrict__ x,
                                                 unsigned short* __restrict__ xT) {
    const size_t gid = (size_t)blockIdx.x * 256 + threadIdx.x;   // 8388608 total
    const int i0 = (int)(gid & 255) * 4;
    const size_t row = gid >> 8;            // dst row = t*64 + b
    const int t = (int)(row >> 6), b = (int)(row & 63);
    const float4 v = *reinterpret_cast<const float4*>(x + (((size_t)b * 512 + t) << 10) + i0);
    ushort4 o;
    o.x = f2bf(v.x); o.y = f2bf(v.y); o.z = f2bf(v.z); o.w = f2bf(v.w);
    *reinterpret_cast<ushort4*>(xT + (row << 10) + i0) = o;
}

// ---------------------------------------------------------------------------
// One LSTM step. grid=64 blocks (16 hidden each), 256 threads (4 waves).
// Fused K=2048: waves 0,1 -> h @ W_h (K 0..1023), waves 2,3 -> x_t @ W_i.
// Each wave: full 64x64 output tile over its 512-wide K slice; LDS reduce.
// ---------------------------------------------------------------------------
__global__ __launch_bounds__(256) void lstm_step(const unsigned short* __restrict__ h_in,
                                                 unsigned short* __restrict__ h_out,
                                                 const unsigned short* __restrict__ xT,
                                                 const unsigned short* __restrict__ Whp,
                                                 const unsigned short* __restrict__ Wip,
                                                 float* __restrict__ c_state,
                                                 int t) {
    const int tid = threadIdx.x;
    const int w = tid >> 6;
    const int lane = tid & 63;
    const int lr = lane & 15;   // row within A/B fragment
    const int kq = lane >> 4;   // k-subslice: k offset = kq*8
    const int blk = blockIdx.x;

    const unsigned short* __restrict__ Ab;
    const unsigned short* __restrict__ Bb;
    int k0;
    if (w < 2) {
        Ab = h_in;
        Bb = Whp + (size_t)blk * (64 * 1024);
        k0 = w * 512;
    } else {
        Ab = xT + (size_t)t * (64 * 1024);
        Bb = Wip + (size_t)blk * (64 * 1024);
        k0 = (w - 2) * 512;
    }

    f32x4 acc[4][4] = {};
    #pragma unroll 4
    for (int it = 0; it < 16; ++it) {
        const int k = k0 + it * 32 + kq * 8;
        bfv8 a[4], b[4];
        #pragma unroll
        for (int m = 0; m < 4; ++m)
            a[m] = *reinterpret_cast<const bfv8*>(Ab + (size_t)(m * 16 + lr) * 1024 + k);
        #pragma unroll
        for (int n = 0; n < 4; ++n)
            b[n] = *reinterpret_cast<const bfv8*>(Bb + (size_t)(n * 16 + lr) * 1024 + k);
        #pragma unroll
        for (int m = 0; m < 4; ++m)
            #pragma unroll
            for (int n = 0; n < 4; ++n)
                acc[m][n] = __builtin_amdgcn_mfma_f32_16x16x32_bf16(a[m], b[n], acc[m][n], 0, 0, 0);
    }

    // cross-wave reduce staging: red[wave][row 0..63][fused col 0..63]
    __shared__ float red[4][64][64];
    #pragma unroll
    for (int m = 0; m < 4; ++m)
        #pragma unroll
        for (int n = 0; n < 4; ++n)
            #pragma unroll
            for (int r = 0; r < 4; ++r)
                red[w][m * 16 + kq * 4 + r][n * 16 + lr] = acc[m][n][r];
    __syncthreads();

    // epilogue: 64 rows x 16 hidden = 1024 items, 4 per thread
    #pragma unroll
    for (int u = 0; u < 4; ++u) {
        const int item = u * 256 + tid;
        const int b = item >> 4;
        const int jr = item & 15;
        float pi = 0.f, pf = 0.f, po = 0.f, pg = 0.f;
        #pragma unroll
        for (int ww = 0; ww < 4; ++ww) {
            pi += red[ww][b][jr];
            pf += red[ww][b][16 + jr];
            po += red[ww][b][32 + jr];
            pg += red[ww][b][48 + jr];
        }
        const int j = blk * 16 + jr;
        const float co = c_state[b * 1024 + j];
        const float ig = 1.f / (1.f + __expf(-pi));
        const float fg = 1.f / (1.f + __expf(-pf));
        const float og = 1.f / (1.f + __expf(-po));
        const float gg = 1.f - 2.f / (__expf(2.f * pg) + 1.f);
        const float cn = fg * co + ig * gg;
        const float hn = og * (1.f - 2.f / (__expf(2.f * cn) + 1.f));
        c_state[b * 1024 + j] = cn;
        h_out[b * 1024 + j] = f2bf(hn);
    }
}

// ---------------------------------------------------------------------------
// out[64][1024] fp32 = h_T (bf16) @ W_y. grid=64 blocks x 16 cols, split-K.
// ---------------------------------------------------------------------------
__global__ __launch_bounds__(256) void final_gemm(const unsigned short* __restrict__ h_in,
                                                  const unsigned short* __restrict__ WyT,
                                                  float* __restrict__ out) {
    const int tid = threadIdx.x;
    const int w = tid >> 6;
    const int lane = tid & 63;
    const int lr = lane & 15;
    const int kq = lane >> 4;
    const int c0 = blockIdx.x * 16;
    const int k0 = w * 256;

    f32x4 acc[4] = {};
    #pragma unroll 2
    for (int it = 0; it < 8; ++it) {
        const int k = k0 + it * 32 + kq * 8;
        const bfv8 bfr = *reinterpret_cast<const bfv8*>(WyT + (size_t)(c0 + lr) * 1024 + k);
        #pragma unroll
        for (int m = 0; m < 4; ++m) {
            const bfv8 a = *reinterpret_cast<const bfv8*>(h_in + (size_t)(m * 16 + lr) * 1024 + k);
            acc[m] = __builtin_amdgcn_mfma_f32_16x16x32_bf16(a, bfr, acc[m], 0, 0, 0);
        }
    }
    __shared__ float red[4][64][16];
    #pragma unroll
    for (int m = 0; m < 4; ++m)
        #pragma unroll
        for (int r = 0; r < 4; ++r)
            red[w][m * 16 + kq * 4 + r][lr] = acc[m][r];
    __syncthreads();
    #pragma unroll
    for (int u = 0; u < 4; ++u) {
        const int item = u * 256 + tid;
        const int b = item >> 4;
        const int jr = item & 15;
        const float s = red[0][b][jr] + red[1][b][jr] + red[2][b][jr] + red[3][b][jr];
        out[b * 1024 + c0 + jr] = s;
    }
}

// ---------------------------------------------------------------------------
extern "C" void kernel_launch(void* const* d_in, const int* in_sizes, int n_in,
                              void* d_out, int out_size, void* d_ws, size_t ws_size,
                              hipStream_t stream) {
    const float* x = (const float*)d_in[0];
    SrcPtrs sp;
    sp.p[0] = (const float*)d_in[1]; // W_hi
    sp.p[1] = (const float*)d_in[3]; // W_hf
    sp.p[2] = (const float*)d_in[5]; // W_ho
    sp.p[3] = (const float*)d_in[7]; // W_hg
    sp.p[4] = (const float*)d_in[2]; // W_ii
    sp.p[5] = (const float*)d_in[4]; // W_if
    sp.p[6] = (const float*)d_in[6]; // W_io
    sp.p[7] = (const float*)d_in[8]; // W_ig
    sp.p[8] = (const float*)d_in[9]; // W_y

    char* ws = (char*)d_ws;
    unsigned short* Whp = (unsigned short*)(ws + 0);          //  8 MB
    unsigned short* Wip = (unsigned short*)(ws + 8388608);    //  8 MB
    unsigned short* Wy  = (unsigned short*)(ws + 16777216);   //  2 MB
    unsigned short* xT  = (unsigned short*)(ws + 18874368);   // 64 MB
    float*          cs  = (float*)(ws + 85983232);            // 256 KB
    unsigned short* h0  = (unsigned short*)(ws + 86245376);   // 128 KB
    unsigned short* h1  = (unsigned short*)(ws + 86376448);   // 128 KB

    pack_weights<<<dim3(16, 16, 9), 256, 0, stream>>>(sp, Whp, Wip, Wy);
    convert_x<<<32768, 256, 0, stream>>>(x, xT);
    hipMemsetAsync(cs, 0, 64 * 1024 * 4, stream);
    hipMemsetAsync(h0, 0, 64 * 1024 * 2, stream);

    unsigned short* hb[2] = {h0, h1};
    for (int t = 0; t < 512; ++t)
        lstm_step<<<64, 256, 0, stream>>>(hb[t & 1], hb[(t + 1) & 1], xT, Whp, Wip, cs, t);

    final_gemm<<<64, 256, 0, stream>>>(h0, Wy, (float*)d_out);
}